// Round 2
// baseline (363.749 us; speedup 1.0000x reference)
//
#include <hip/hip_runtime.h>
#include <hip/hip_bf16.h>

#define N_ROWS 200000
#define F 256
#define NGRAPH 64
#define BM 64
#define SSCALE 1.6666666666666667f

typedef __attribute__((ext_vector_type(8))) short short8;   // 8 bf16 (4 VGPRs)
typedef __attribute__((ext_vector_type(4))) float f32x4;    // MFMA C/D frag

__device__ __forceinline__ unsigned short f2bf(float f) {
    unsigned int u = __float_as_uint(f);
    u = (u + 0x7fffu + ((u >> 16) & 1u)) >> 16;   // RNE
    return (unsigned short)u;
}
__device__ __forceinline__ float bf2f(unsigned short v) {
    return __uint_as_float(((unsigned int)v) << 16);
}
__device__ __forceinline__ float ssilu_f(float s) {
    return s / (1.0f + __expf(-s)) * SSCALE;
}

// ---- weight convert + transpose: W[K][256] f32 -> out[256][K] bf16 ----
__global__ void cvt_transpose(const float* __restrict__ W, unsigned short* __restrict__ out,
                              int logK) {
    int K = 1 << logK;
    int idx = blockIdx.x * 256 + threadIdx.x;
    int n = idx >> logK;
    int k = idx & (K - 1);
    out[idx] = f2bf(W[k * 256 + n]);
}

// ---- zero sums + per-graph counts (batch sorted) ----
__global__ void prep_kernel(const int* __restrict__ batch, float* __restrict__ sums,
                            int* __restrict__ counts) {
    int b = blockIdx.x, t = threadIdx.x;
    sums[b * 256 + t] = 0.0f;
    if (t == 0) {
        int lo = 0, hi = N_ROWS;
        while (lo < hi) { int m = (lo + hi) >> 1; if (batch[m] < b) lo = m + 1; else hi = m; }
        int lb = lo;
        lo = 0; hi = N_ROWS;
        while (lo < hi) { int m = (lo + hi) >> 1; if (batch[m] < b + 1) lo = m + 1; else hi = m; }
        counts[b] = lo - lb;
    }
}

// ---- main fused node-MLP kernel ----
__global__ __launch_bounds__(256, 2) void node_kernel(
    const float* __restrict__ x, const int* __restrict__ batch,
    const float* __restrict__ vx,
    const unsigned short* __restrict__ wnt1,  // [256][512] bf16 (N-major)
    const float* __restrict__ bn1,
    const unsigned short* __restrict__ wnt2,  // [256][256] bf16
    const float* __restrict__ bn2,
    float* __restrict__ hout, float* __restrict__ sums)
{
    __shared__ unsigned short xa[BM * 256];    // x tile, bf16, swizzled
    __shared__ unsigned short buf2[BM * 256];  // vx[batch] tile, then h1 tile

    const int t = threadIdx.x;
    const int r0 = blockIdx.x * BM;

    // ---- stage: x and vx[batch] -> LDS bf16 (swizzled) ----
    #pragma unroll
    for (int i = 0; i < 16; ++i) {
        int flat = (t + i * 256) * 4;           // element in 64x256 tile
        int row = flat >> 8;
        int col = flat & 255;
        float4 v = *reinterpret_cast<const float4*>(&x[(size_t)(r0 + row) * 256 + col]);
        int e = ((row << 8) + col) ^ ((row & 7) << 3);
        ushort4 u;
        u.x = f2bf(v.x); u.y = f2bf(v.y); u.z = f2bf(v.z); u.w = f2bf(v.w);
        *reinterpret_cast<ushort4*>(&xa[e]) = u;
        int b = batch[r0 + row];
        float4 w = *reinterpret_cast<const float4*>(&vx[b * 256 + col]);
        ushort4 u2;
        u2.x = f2bf(w.x); u2.y = f2bf(w.y); u2.z = f2bf(w.z); u2.w = f2bf(w.w);
        *reinterpret_cast<ushort4*>(&buf2[e]) = u2;
    }
    __syncthreads();

    const int lane = t & 63;
    const int wave = t >> 6;
    const int lr = lane & 15;
    const int lg = lane >> 4;
    const int wcol = wave * 64;

    f32x4 zero4 = {0.f, 0.f, 0.f, 0.f};
    f32x4 acc[4][4];
    #pragma unroll
    for (int m = 0; m < 4; ++m)
        #pragma unroll
        for (int n = 0; n < 4; ++n) acc[m][n] = zero4;

    // ---- GEMM1: [64 x 512] @ [512 x 256] ----
    #pragma unroll
    for (int kk = 0; kk < 16; ++kk) {
        int kc = kk * 32 + lg * 8;
        const unsigned short* ab = (kk < 8) ? xa : buf2;
        int kl = (kk < 8) ? kc : (kc - 256);
        short8 af[4], bfg[4];
        #pragma unroll
        for (int m = 0; m < 4; ++m) {
            int row = m * 16 + lr;
            int e = ((row << 8) + kl) ^ ((row & 7) << 3);
            af[m] = *reinterpret_cast<const short8*>(&ab[e]);
        }
        #pragma unroll
        for (int n = 0; n < 4; ++n) {
            int nr = wcol + n * 16 + lr;
            bfg[n] = *reinterpret_cast<const short8*>(&wnt1[nr * 512 + kc]);
        }
        #pragma unroll
        for (int m = 0; m < 4; ++m)
            #pragma unroll
            for (int n = 0; n < 4; ++n)
                acc[m][n] = __builtin_amdgcn_mfma_f32_16x16x32_bf16(af[m], bfg[n], acc[m][n], 0, 0, 0);
    }

    // ---- h1 = ssilu(acc + bn1) -> bf16 into buf2 (vx tile is dead) ----
    __syncthreads();
    #pragma unroll
    for (int n = 0; n < 4; ++n) {
        int col = wcol + n * 16 + lr;
        float bias = bn1[col];
        #pragma unroll
        for (int m = 0; m < 4; ++m) {
            #pragma unroll
            for (int r = 0; r < 4; ++r) {
                int row = m * 16 + lg * 4 + r;
                float hv = ssilu_f(acc[m][n][r] + bias);
                int e = ((row << 8) + col) ^ ((row & 7) << 3);
                buf2[e] = f2bf(hv);
            }
        }
    }
    __syncthreads();

    // ---- GEMM2: [64 x 256] @ [256 x 256] ----
    f32x4 acc2[4][4];
    #pragma unroll
    for (int m = 0; m < 4; ++m)
        #pragma unroll
        for (int n = 0; n < 4; ++n) acc2[m][n] = zero4;

    #pragma unroll
    for (int kk = 0; kk < 8; ++kk) {
        int kc = kk * 32 + lg * 8;
        short8 af[4], bfg[4];
        #pragma unroll
        for (int m = 0; m < 4; ++m) {
            int row = m * 16 + lr;
            int e = ((row << 8) + kc) ^ ((row & 7) << 3);
            af[m] = *reinterpret_cast<const short8*>(&buf2[e]);
        }
        #pragma unroll
        for (int n = 0; n < 4; ++n) {
            int nr = wcol + n * 16 + lr;
            bfg[n] = *reinterpret_cast<const short8*>(&wnt2[nr * 256 + kc]);
        }
        #pragma unroll
        for (int m = 0; m < 4; ++m)
            #pragma unroll
            for (int n = 0; n < 4; ++n)
                acc2[m][n] = __builtin_amdgcn_mfma_f32_16x16x32_bf16(af[m], bfg[n], acc2[m][n], 0, 0, 0);
    }

    // ---- epilogue: h = ssilu(acc2 + bn2) + x ; write + pooled sums ----
    const bool multi = (batch[r0] != batch[r0 + BM - 1]);
    const int bfst = batch[r0];
    float ps[4] = {0.f, 0.f, 0.f, 0.f};

    #pragma unroll
    for (int n = 0; n < 4; ++n) {
        int col = wcol + n * 16 + lr;
        float bias = bn2[col];
        #pragma unroll
        for (int m = 0; m < 4; ++m) {
            #pragma unroll
            for (int r = 0; r < 4; ++r) {
                int row = m * 16 + lg * 4 + r;
                float hv = ssilu_f(acc2[m][n][r] + bias);
                int e = ((row << 8) + col) ^ ((row & 7) << 3);
                hv += bf2f(xa[e]);                       // residual (bf16 x)
                hout[(size_t)(r0 + row) * 256 + col] = hv;
                if (!multi) ps[n] += hv;
                else atomicAdd(&sums[batch[r0 + row] * 256 + col], hv);
            }
        }
    }
    if (!multi) {
        #pragma unroll
        for (int n = 0; n < 4; ++n) {
            float p = ps[n];
            p += __shfl_xor(p, 16);
            p += __shfl_xor(p, 32);
            if (lane < 16) atomicAdd(&sums[bfst * 256 + wcol + n * 16 + lane], p);
        }
    }
}

// ---- virtual-node MLP layer 1: v = ssilu(cat(pooled, vx) @ Wv1 + bv1) ----
// writes v into the vout region of d_out (scratch reuse; overwritten by vmlp2)
__global__ void vmlp1(const float* __restrict__ sums, const int* __restrict__ counts,
                      const float* __restrict__ vx, const float* __restrict__ Wv1,
                      const float* __restrict__ bv1, float* __restrict__ v) {
    __shared__ float cat[512];
    int b = blockIdx.x, t = threadIdx.x;
    float cnt = fmaxf((float)counts[b], 1.0f);
    cat[t] = sums[b * 256 + t] / cnt;
    cat[t + 256] = vx[b * 256 + t];
    __syncthreads();
    float a = 0.f;
    #pragma unroll 8
    for (int k = 0; k < 512; ++k) a = fmaf(cat[k], Wv1[k * 256 + t], a);
    a += bv1[t];
    v[b * 256 + t] = ssilu_f(a);
}

// ---- virtual-node MLP layer 2: vx_new = ssilu(v @ Wv2 + bv2) ----
// v lives in the vout region; staged to LDS before being overwritten (block-local)
__global__ void vmlp2(const float* __restrict__ v, const float* __restrict__ Wv2,
                      const float* __restrict__ bv2, float* __restrict__ out) {
    __shared__ float rowv[256];
    int b = blockIdx.x, t = threadIdx.x;
    rowv[t] = v[b * 256 + t];
    __syncthreads();
    float a = 0.f;
    #pragma unroll 8
    for (int k = 0; k < 256; ++k) a = fmaf(rowv[k], Wv2[k * 256 + t], a);
    a += bv2[t];
    out[b * 256 + t] = ssilu_f(a);
}

extern "C" void kernel_launch(void* const* d_in, const int* in_sizes, int n_in,
                              void* d_out, int out_size, void* d_ws, size_t ws_size,
                              hipStream_t stream) {
    const float* x   = (const float*)d_in[0];
    const int*   batch = (const int*)d_in[1];
    const float* vx  = (const float*)d_in[2];
    const float* Wn1 = (const float*)d_in[3];
    const float* bn1 = (const float*)d_in[4];
    const float* Wn2 = (const float*)d_in[5];
    const float* bn2 = (const float*)d_in[6];
    const float* Wv1 = (const float*)d_in[7];
    const float* bv1 = (const float*)d_in[8];
    const float* Wv2 = (const float*)d_in[9];
    const float* bv2 = (const float*)d_in[10];

    float* hout = (float*)d_out;
    float* vout = hout + (size_t)N_ROWS * F;   // also reused as v-scratch

    // ws layout — total 459,008 B (must stay under 512 KiB)
    char* ws = (char*)d_ws;
    unsigned short* wnt1   = (unsigned short*)(ws);           // 256*512*2 = 262144
    unsigned short* wnt2   = (unsigned short*)(ws + 262144);  // 256*256*2 = 131072
    float*          sums   = (float*)(ws + 393216);           // 64*256*4  = 65536
    int*            counts = (int*)(ws + 458752);             // 256

    cvt_transpose<<<512, 256, 0, stream>>>(Wn1, wnt1, 9);
    cvt_transpose<<<256, 256, 0, stream>>>(Wn2, wnt2, 8);
    prep_kernel<<<NGRAPH, 256, 0, stream>>>(batch, sums, counts);
    node_kernel<<<N_ROWS / BM, 256, 0, stream>>>(x, batch, vx, wnt1, bn1, wnt2, bn2, hout, sums);
    vmlp1<<<NGRAPH, 256, 0, stream>>>(sums, counts, vx, Wv1, bv1, vout);
    vmlp2<<<NGRAPH, 256, 0, stream>>>(vout, Wv2, bv2, vout);
}